// Round 11
// baseline (234.247 us; speedup 1.0000x reference)
//
#include <hip/hip_runtime.h>
#include <hip/hip_bf16.h>
#include <stdint.h>

#define N_NODES   16384
#define DIMM      256
#define HEADS     8
#define HDIM      32
#define NUM_GLOBAL 4
#define N_TOT     (N_NODES + NUM_GLOBAL)   // 16388
#define E_LOCAL   131072
#define E_EXP     65536
#define E_CSR     (E_LOCAL + E_EXP)        // 196608

typedef __hip_bfloat16 bf16;
typedef __attribute__((ext_vector_type(8))) short short8;
typedef __attribute__((ext_vector_type(4))) short sh4;
typedef __attribute__((ext_vector_type(4))) float f32x4;

__device__ __forceinline__ short f2s(float f) {
    bf16 h = __float2bfloat16(f);
    return __builtin_bit_cast(short, h);
}
__device__ __forceinline__ float bu2f(unsigned short u) {
    return __bfloat162float(__builtin_bit_cast(bf16, u));
}

// ---------------------------------------------------------------------------
// prep: (a) transpose Wqkv (256x768 fp32) -> Wt1 bf16 [768][256]
//       (b) transpose Wout (256x256 fp32) -> Wt2 bf16 [256][256]
//       (c) count_edges into cnt (dst-keyed; n2g edges skipped)
// blocks 0..47 = (a), 48..63 = (b), 64..831 = (c).
// ---------------------------------------------------------------------------
__global__ __launch_bounds__(256) void prep_kernel(
    const float* __restrict__ Wqkv, const float* __restrict__ Wout,
    const int* __restrict__ ei, const int* __restrict__ xei,
    bf16* __restrict__ Wt1, bf16* __restrict__ Wt2, int* __restrict__ cnt)
{
    const int b = blockIdx.x;
    const int t = threadIdx.x;
    if (b < 64) {
        __shared__ float T[64][65];
        const float* src; bf16* dst; int n0, k0, ldn;
        if (b < 48) { src = Wqkv; dst = Wt1; n0 = (b % 12) * 64; k0 = (b / 12) * 64; ldn = 768; }
        else        { int bb = b - 48; src = Wout; dst = Wt2; n0 = (bb & 3) * 64; k0 = (bb >> 2) * 64; ldn = 256; }
        #pragma unroll
        for (int i = 0; i < 4; ++i) {
            int idx = t + 256 * i;
            int r = idx >> 4, c4 = (idx & 15) * 4;
            float4 v = *(const float4*)(src + (size_t)(k0 + r) * ldn + n0 + c4);
            T[r][c4] = v.x; T[r][c4 + 1] = v.y; T[r][c4 + 2] = v.z; T[r][c4 + 3] = v.w;
        }
        __syncthreads();
        #pragma unroll
        for (int i = 0; i < 4; ++i) {
            int idx = t + 256 * i;
            int nr = idx >> 4, kk = (idx & 15) * 4;
            sh4 o;
            o[0] = f2s(T[kk][nr]);     o[1] = f2s(T[kk + 1][nr]);
            o[2] = f2s(T[kk + 2][nr]); o[3] = f2s(T[kk + 3][nr]);
            *(sh4*)(dst + (size_t)(n0 + nr) * 256 + k0 + kk) = o;
        }
    } else {
        int e = (b - 64) * 256 + t;
        if (e < E_LOCAL)      atomicAdd(&cnt[ei[E_LOCAL + e]], 1);
        else if (e < E_CSR) { int ee = e - E_LOCAL; atomicAdd(&cnt[xei[E_EXP + ee]], 1); }
    }
}

// ---------------------------------------------------------------------------
// QKV projection (MFMA, A-resident): each block owns a 16-row slab of X,
// stages it ONCE into LDS (bf16, bank-swizzled), then loops over all 12
// n-tiles (wave w -> nt = 3w..3w+2). B-fragments are register-direct short8
// loads from the pre-transposed L2-hot Wt1 -- no LDS, no extra barrier.
// X is fetched from HBM exactly once (R10 fetched it ~4x).
// ---------------------------------------------------------------------------
__global__ __launch_bounds__(256) void qkv_mfma(
    const float* __restrict__ x, const float* __restrict__ gtok,
    const bf16* __restrict__ Wt, const float* __restrict__ bias,
    float* __restrict__ Q, bf16* __restrict__ Kb, bf16* __restrict__ Vb)
{
    __shared__ short As[16 * 256];   // 8 KB, [r][k] in 32 chunks of 8, low-3-bit swizzle
    const int t = threadIdx.x;
    const int m0 = blockIdx.x * 16;
    const int w = t >> 6, lane = t & 63;
    const int lm = lane & 15, lq = lane >> 4;

    // stage A: 16 rows x 256 k = 512 chunks; 2 per thread, coalesced
    #pragma unroll
    for (int i = 0; i < 2; ++i) {
        int c8 = t + 256 * i;
        int r = c8 >> 5, kc = c8 & 31;
        int row = m0 + r;
        float4 v0 = make_float4(0.f, 0.f, 0.f, 0.f), v1 = v0;
        if (row < N_NODES) {
            const float* p = x + (size_t)row * DIMM + kc * 8;
            v0 = *(const float4*)p; v1 = *(const float4*)(p + 4);
        } else if (row < N_TOT) {
            const float* p = gtok + (size_t)(row - N_NODES) * DIMM + kc * 8;
            v0 = *(const float4*)p; v1 = *(const float4*)(p + 4);
        }
        short8 o;
        o[0] = f2s(v0.x); o[1] = f2s(v0.y); o[2] = f2s(v0.z); o[3] = f2s(v0.w);
        o[4] = f2s(v1.x); o[5] = f2s(v1.y); o[6] = f2s(v1.z); o[7] = f2s(v1.w);
        int pc = (kc & 24) | ((kc & 7) ^ (r & 7));
        *(short8*)(As + r * 256 + pc * 8) = o;
    }
    __syncthreads();

    for (int nt = w * 3; nt < w * 3 + 3; ++nt) {
        const int n0 = nt * 64;
        f32x4 acc[4] = {};
        #pragma unroll
        for (int kb = 0; kb < 8; ++kb) {
            int ck = kb * 4 + lq;
            int pc = (ck & 24) | ((ck & 7) ^ (lm & 7));
            short8 af = *(const short8*)(As + lm * 256 + pc * 8);
            #pragma unroll
            for (int ni = 0; ni < 4; ++ni) {
                int n = n0 + ni * 16 + lm;
                short8 bf = *(const short8*)((const short*)Wt + (size_t)n * 256 + ck * 8);
                acc[ni] = __builtin_amdgcn_mfma_f32_16x16x32_bf16(af, bf, acc[ni], 0, 0, 0);
            }
        }
        // epilogue: C col = lm (within 16), row = lq*4+rr
        const int sel = n0 >> 8;                 // 0=Q 1=K 2=V
        #pragma unroll
        for (int ni = 0; ni < 4; ++ni) {
            int col = n0 + ni * 16 + lm;
            float bv = bias[col];
            int cc = col & 255;
            #pragma unroll
            for (int rr = 0; rr < 4; ++rr) {
                int row = m0 + lq * 4 + rr;
                if (row >= N_TOT) continue;
                float val = acc[ni][rr] + bv;
                if (sel == 0)      Q [(size_t)row * DIMM + cc] = val;
                else if (sel == 1) Kb[(size_t)row * DIMM + cc] = __float2bfloat16(val);
                else               Vb[(size_t)row * DIMM + cc] = __float2bfloat16(val);
            }
        }
    }
}

// ---------------------------------------------------------------------------
// Output projection (MFMA, A-resident): O(16384x256 bf16) @ Wout + bout ->
// out fp32. Same structure; 4 waves cover all 256 cols (nt = w).
// ---------------------------------------------------------------------------
__global__ __launch_bounds__(256) void out_mfma(
    const bf16* __restrict__ O, const bf16* __restrict__ Wt,
    const float* __restrict__ bias, float* __restrict__ out)
{
    __shared__ short As[16 * 256];
    const int t = threadIdx.x;
    const int m0 = blockIdx.x * 16;
    const int w = t >> 6, lane = t & 63;
    const int lm = lane & 15, lq = lane >> 4;

    #pragma unroll
    for (int i = 0; i < 2; ++i) {
        int c8 = t + 256 * i;
        int r = c8 >> 5, kc = c8 & 31;
        short8 v = *(const short8*)((const short*)O + (size_t)(m0 + r) * DIMM + kc * 8);
        int pc = (kc & 24) | ((kc & 7) ^ (r & 7));
        *(short8*)(As + r * 256 + pc * 8) = v;
    }
    __syncthreads();

    const int n0 = w * 64;
    f32x4 acc[4] = {};
    #pragma unroll
    for (int kb = 0; kb < 8; ++kb) {
        int ck = kb * 4 + lq;
        int pc = (ck & 24) | ((ck & 7) ^ (lm & 7));
        short8 af = *(const short8*)(As + lm * 256 + pc * 8);
        #pragma unroll
        for (int ni = 0; ni < 4; ++ni) {
            int n = n0 + ni * 16 + lm;
            short8 bf = *(const short8*)((const short*)Wt + (size_t)n * 256 + ck * 8);
            acc[ni] = __builtin_amdgcn_mfma_f32_16x16x32_bf16(af, bf, acc[ni], 0, 0, 0);
        }
    }
    #pragma unroll
    for (int ni = 0; ni < 4; ++ni) {
        int col = n0 + ni * 16 + lm;
        float bv = bias[col];
        #pragma unroll
        for (int rr = 0; rr < 4; ++rr) {
            int row = m0 + lq * 4 + rr;
            float val = acc[ni][rr] + bv;
            val = fminf(fmaxf(val, -1e4f), 1e4f);  // tripwire (no-op valid)
            out[(size_t)row * DIMM + col] = val;
        }
    }
}

// ---------------------------------------------------------------------------
// CSR scan + fill (count lives in prep_kernel).
// ---------------------------------------------------------------------------
__global__ void scan_kernel(int* __restrict__ cnt_cursor, int* __restrict__ rowstart)
{
    __shared__ int part[256];
    const int t = threadIdx.x;
    const int base = t * 64;
    int s = 0;
    for (int i = 0; i < 64; ++i) s += cnt_cursor[base + i];
    part[t] = s;
    __syncthreads();
    for (int off = 1; off < 256; off <<= 1) {
        int v = (t >= off) ? part[t - off] : 0;
        __syncthreads();
        part[t] += v;
        __syncthreads();
    }
    int excl = part[t] - s;
    for (int i = 0; i < 64; ++i) {
        int v = cnt_cursor[base + i];
        rowstart[base + i]   = excl;
        cnt_cursor[base + i] = excl;
        excl += v;
    }
    if (t == 255) rowstart[N_NODES] = excl;
}

__global__ void fill_edges(const int* __restrict__ ei, const int* __restrict__ xei,
                           int* __restrict__ cursor, int* __restrict__ adj)
{
    int e = blockIdx.x * blockDim.x + threadIdx.x;
    int s, d;
    if (e < E_LOCAL)      { s = ei[e];            d = ei[E_LOCAL + e]; }
    else if (e < E_CSR)   { int ee = e - E_LOCAL; s = xei[ee]; d = xei[E_EXP + ee]; }
    else return;
    int pos = atomicAdd(&cursor[d], 1);
    adj[pos] = s;
}

// ---------------------------------------------------------------------------
// Gather attention: one wave per dst node; bf16 K/V; 4-edge unroll (8 gather
// loads in flight). Virtual edge index domain [rs-5, re): -5=self,
// -4..-1=globals, >=0 = adj[i]. Tripwires are no-ops on valid data.
// ---------------------------------------------------------------------------
__global__ __launch_bounds__(256) void attn_kernel(
    const float* __restrict__ Q, const bf16* __restrict__ Kb,
    const bf16* __restrict__ Vb, const int* __restrict__ rowstart,
    const int* __restrict__ adj, bf16* __restrict__ Ob)
{
    const int wave = (blockIdx.x * blockDim.x + threadIdx.x) >> 6;
    const int lane = threadIdx.x & 63;
    if (wave >= N_NODES) return;
    const int n = wave;
    const float scale = 0.1767766952966369f;  // 32^-0.5

    const ushort4* K4 = (const ushort4*)Kb;
    const ushort4* V4 = (const ushort4*)Vb;

    float4 q = ((const float4*)(Q + (size_t)n * DIMM))[lane];
    q.x *= scale; q.y *= scale; q.z *= scale; q.w *= scale;

    float4 acc = make_float4(0.f, 0.f, 0.f, 0.f);
    float dsum = 0.f;

    const int rs = rowstart[n];
    const int re = rowstart[n + 1];

    for (int i = rs - 5; i < re; i += 4) {
        int   sv[4];
        float ok[4];
        #pragma unroll
        for (int u = 0; u < 4; ++u) {
            int ii = i + u;
            bool v = (ii < re);
            int d = ii - rs;
            int s = v ? ((d < 0) ? ((d == -5) ? n : (N_NODES + d + 4)) : adj[ii]) : 0;
            sv[u] = min(max(s, 0), N_TOT - 1);
            ok[u] = v ? 1.f : 0.f;
        }
        ushort4 kv[4], vv[4];
        #pragma unroll
        for (int u = 0; u < 4; ++u) kv[u] = K4[(size_t)sv[u] * 64 + lane];
        #pragma unroll
        for (int u = 0; u < 4; ++u) vv[u] = V4[(size_t)sv[u] * 64 + lane];

        float p[4];
        #pragma unroll
        for (int u = 0; u < 4; ++u)
            p[u] = q.x * bu2f(kv[u].x) + q.y * bu2f(kv[u].y)
                 + q.z * bu2f(kv[u].z) + q.w * bu2f(kv[u].w);
        #pragma unroll
        for (int u = 0; u < 4; ++u) {
            p[u] += __shfl_xor(p[u], 1);
            p[u] += __shfl_xor(p[u], 2);
            p[u] += __shfl_xor(p[u], 4);
        }
        #pragma unroll
        for (int u = 0; u < 4; ++u) {
            float wgt = ok[u] * __expf(fminf(p[u], 80.f));
            dsum += wgt;
            acc.x += wgt * bu2f(vv[u].x);
            acc.y += wgt * bu2f(vv[u].y);
            acc.z += wgt * bu2f(vv[u].z);
            acc.w += wgt * bu2f(vv[u].w);
        }
    }

    float r = 1.0f / fmaxf(dsum, 1e-30f);    // tripwire
    ushort4 o;
    o.x = (unsigned short)__builtin_bit_cast(short, __float2bfloat16(fminf(fmaxf(acc.x * r, -500.f), 500.f)));
    o.y = (unsigned short)__builtin_bit_cast(short, __float2bfloat16(fminf(fmaxf(acc.y * r, -500.f), 500.f)));
    o.z = (unsigned short)__builtin_bit_cast(short, __float2bfloat16(fminf(fmaxf(acc.z * r, -500.f), 500.f)));
    o.w = (unsigned short)__builtin_bit_cast(short, __float2bfloat16(fminf(fmaxf(acc.w * r, -500.f), 500.f)));
    ((ushort4*)Ob)[(size_t)n * 64 + lane] = o;
}

// ---------------------------------------------------------------------------
extern "C" void kernel_launch(void* const* d_in, const int* in_sizes, int n_in,
                              void* d_out, int out_size, void* d_ws, size_t ws_size,
                              hipStream_t stream)
{
    const float* x    = (const float*)d_in[0];
    const int*   ei   = (const int*)d_in[1];
    const int*   xei  = (const int*)d_in[2];
    const float* Wqkv = (const float*)d_in[3];
    const float* bqkv = (const float*)d_in[4];
    const float* Wout = (const float*)d_in[5];
    const float* bout = (const float*)d_in[6];
    const float* gtok = (const float*)d_in[7];

    // workspace layout (~43.8 MB; ws >= 51.3 MB proven):
    int* rowstart = (int*)d_ws;               // N_NODES+1
    int* cursor   = rowstart + (N_NODES + 1); // N_NODES
    int* adj      = cursor + N_NODES;         // E_CSR
    const size_t int_bytes = (size_t)(N_NODES + 1 + N_NODES + E_CSR) * sizeof(int);
    uintptr_t fb = ((uintptr_t)(adj + E_CSR) + 15) & ~(uintptr_t)15;
    float* Q   = (float*)fb;                        // fp32, N_TOT*256
    bf16*  Kb  = (bf16*)(Q + (size_t)N_TOT * DIMM); // bf16, N_TOT*256
    bf16*  Vb  = Kb + (size_t)N_TOT * DIMM;         // bf16, N_TOT*256
    bf16*  Ob  = Vb + (size_t)N_TOT * DIMM;         // bf16, N_NODES*256
    bf16*  Wt1 = Ob + (size_t)N_NODES * DIMM;       // bf16, 768*256
    bf16*  Wt2 = Wt1 + 768 * 256;                   // bf16, 256*256

    hipMemsetAsync(d_ws, 0, int_bytes, stream);

    prep_kernel<<<832, 256, 0, stream>>>(Wqkv, Wout, ei, xei, Wt1, Wt2, cursor);
    scan_kernel<<<1, 256, 0, stream>>>(cursor, rowstart);
    fill_edges<<<(E_CSR + 255) / 256, 256, 0, stream>>>(ei, xei, cursor, adj);
    qkv_mfma<<<(N_TOT + 15) / 16, 256, 0, stream>>>(x, gtok, Wt1, bqkv, Q, Kb, Vb);
    attn_kernel<<<N_NODES / 4, 256, 0, stream>>>(Q, Kb, Vb, rowstart, adj, Ob);
    out_mfma<<<N_NODES / 16, 256, 0, stream>>>(Ob, Wt2, bout, (float*)d_out);
}

// Round 12
// 196.289 us; speedup vs baseline: 1.1934x; 1.1934x over previous
//
#include <hip/hip_runtime.h>
#include <hip/hip_bf16.h>
#include <stdint.h>

#define N_NODES   16384
#define DIMM      256
#define HEADS     8
#define HDIM      32
#define NUM_GLOBAL 4
#define N_TOT     (N_NODES + NUM_GLOBAL)   // 16388
#define E_LOCAL   131072
#define E_EXP     65536
#define E_CSR     (E_LOCAL + E_EXP)        // 196608

typedef __hip_bfloat16 bf16;
typedef __attribute__((ext_vector_type(8))) short short8;
typedef __attribute__((ext_vector_type(4))) short sh4;
typedef __attribute__((ext_vector_type(4))) float f32x4;

__device__ __forceinline__ short f2s(float f) {
    bf16 h = __float2bfloat16(f);
    return __builtin_bit_cast(short, h);
}
__device__ __forceinline__ float bu2f(unsigned short u) {
    return __bfloat162float(__builtin_bit_cast(bf16, u));
}

// XOR swizzle: 16B chunk c of row r stored at chunk (c ^ (r&7) ^ ((r>>3)&7)).
__device__ __forceinline__ int swz(int c, int r) {
    return c ^ (r & 7) ^ ((r >> 3) & 7);
}

// ---------------------------------------------------------------------------
// prep: (a) transpose Wqkv (256x768 fp32) -> Wt1 bf16 [768][256]
//       (b) transpose Wout (256x256 fp32) -> Wt2 bf16 [256][256]
//       (c) count_edges into cnt (dst-keyed; n2g edges skipped)
// ---------------------------------------------------------------------------
__global__ __launch_bounds__(256) void prep_kernel(
    const float* __restrict__ Wqkv, const float* __restrict__ Wout,
    const int* __restrict__ ei, const int* __restrict__ xei,
    bf16* __restrict__ Wt1, bf16* __restrict__ Wt2, int* __restrict__ cnt)
{
    const int b = blockIdx.x;
    const int t = threadIdx.x;
    if (b < 64) {
        __shared__ float T[64][65];
        const float* src; bf16* dst; int n0, k0, ldn;
        if (b < 48) { src = Wqkv; dst = Wt1; n0 = (b % 12) * 64; k0 = (b / 12) * 64; ldn = 768; }
        else        { int bb = b - 48; src = Wout; dst = Wt2; n0 = (bb & 3) * 64; k0 = (bb >> 2) * 64; ldn = 256; }
        #pragma unroll
        for (int i = 0; i < 4; ++i) {
            int idx = t + 256 * i;
            int r = idx >> 4, c4 = (idx & 15) * 4;
            float4 v = *(const float4*)(src + (size_t)(k0 + r) * ldn + n0 + c4);
            T[r][c4] = v.x; T[r][c4 + 1] = v.y; T[r][c4 + 2] = v.z; T[r][c4 + 3] = v.w;
        }
        __syncthreads();
        #pragma unroll
        for (int i = 0; i < 4; ++i) {
            int idx = t + 256 * i;
            int nr = idx >> 4, kk = (idx & 15) * 4;
            sh4 o;
            o[0] = f2s(T[kk][nr]);     o[1] = f2s(T[kk + 1][nr]);
            o[2] = f2s(T[kk + 2][nr]); o[3] = f2s(T[kk + 3][nr]);
            *(sh4*)(dst + (size_t)(n0 + nr) * 256 + k0 + kk) = o;
        }
    } else {
        int e = (b - 64) * 256 + t;
        if (e < E_LOCAL)      atomicAdd(&cnt[ei[E_LOCAL + e]], 1);
        else if (e < E_CSR) { int ee = e - E_LOCAL; atomicAdd(&cnt[xei[E_EXP + ee]], 1); }
    }
}

// ---------------------------------------------------------------------------
// QKV projection (MFMA): X_full(16388x256 fp32) @ Wqkv + b -> Q,K,V bf16.
// R9's proven 128x128 tile / BK=64 / 4 waves (2x2) / 4x4 frags. B staged as
// direct short8 copies from pre-transposed bf16 Wt1 [n][k] (no f2s, half
// the W fetch of R9). Q now bf16 (halves qkv writes + attn Q reads).
// ---------------------------------------------------------------------------
__global__ __launch_bounds__(256) void qkv_mfma(
    const float* __restrict__ x, const float* __restrict__ gtok,
    const bf16* __restrict__ Wt, const float* __restrict__ bias,
    bf16* __restrict__ Qb, bf16* __restrict__ Kb, bf16* __restrict__ Vb)
{
    __shared__ short As[128 * 64];   // [m][k] bf16, swizzled 16B chunks
    __shared__ short Bs[128 * 64];   // [n][k] bf16, swizzled
    const int t  = threadIdx.x;
    const int m0 = blockIdx.y * 128;
    const int n0 = blockIdx.x * 128;           // 0..640
    const int wid = t >> 6, lane = t & 63;
    const int wr = wid >> 1, wc = wid & 1;
    const int lm = lane & 15, lq = lane >> 4;

    f32x4 acc[4][4] = {};

    for (int k0 = 0; k0 < DIMM; k0 += 64) {
        if (k0) __syncthreads();
        // --- stage A: 128 rows x 64 k; 4 short8 per thread (fp32->bf16) ---
        #pragma unroll
        for (int i = 0; i < 4; ++i) {
            int c8 = t + 256 * i;
            int r  = c8 >> 3, kc = c8 & 7;
            int row = m0 + r;
            float4 v0 = make_float4(0.f, 0.f, 0.f, 0.f), v1 = v0;
            if (row < N_NODES) {
                const float* p = x + (size_t)row * DIMM + k0 + kc * 8;
                v0 = *(const float4*)p; v1 = *(const float4*)(p + 4);
            } else if (row < N_TOT) {
                const float* p = gtok + (size_t)(row - N_NODES) * DIMM + k0 + kc * 8;
                v0 = *(const float4*)p; v1 = *(const float4*)(p + 4);
            }
            short8 o;
            o[0] = f2s(v0.x); o[1] = f2s(v0.y); o[2] = f2s(v0.z); o[3] = f2s(v0.w);
            o[4] = f2s(v1.x); o[5] = f2s(v1.y); o[6] = f2s(v1.z); o[7] = f2s(v1.w);
            *(short8*)(As + r * 64 + swz(kc, r) * 8) = o;
        }
        // --- stage B: direct short8 copy from Wt[n][k] ---
        #pragma unroll
        for (int i = 0; i < 4; ++i) {
            int c8 = t + 256 * i;
            int n  = c8 >> 3, kc = c8 & 7;
            short8 v = *(const short8*)((const short*)Wt + (size_t)(n0 + n) * 256 + k0 + kc * 8);
            *(short8*)(Bs + n * 64 + swz(kc, n) * 8) = v;
        }
        __syncthreads();
        #pragma unroll
        for (int kk = 0; kk < 2; ++kk) {
            const int c = kk * 4 + lq;
            short8 af[4], bfq[4];
            #pragma unroll
            for (int mi = 0; mi < 4; ++mi) {
                int r = wr * 64 + mi * 16 + lm;
                af[mi] = *(const short8*)(As + r * 64 + swz(c, r) * 8);
            }
            #pragma unroll
            for (int ni = 0; ni < 4; ++ni) {
                int n = wc * 64 + ni * 16 + lm;
                bfq[ni] = *(const short8*)(Bs + n * 64 + swz(c, n) * 8);
            }
            #pragma unroll
            for (int mi = 0; mi < 4; ++mi)
                #pragma unroll
                for (int ni = 0; ni < 4; ++ni)
                    acc[mi][ni] = __builtin_amdgcn_mfma_f32_16x16x32_bf16(
                        af[mi], bfq[ni], acc[mi][ni], 0, 0, 0);
        }
    }

    // --- epilogue: C col = lm, row = lq*4+rr; 64-col stripe -> one of Q/K/V
    const int colbase = n0 + wc * 64;
    const int sel = colbase >> 8;                 // 0=Q 1=K 2=V
    bf16* __restrict__ dst = (sel == 0) ? Qb : (sel == 1) ? Kb : Vb;
    #pragma unroll
    for (int ni = 0; ni < 4; ++ni) {
        int col = colbase + ni * 16 + lm;
        float bv = bias[col];
        int cc = col & 255;
        #pragma unroll
        for (int mi = 0; mi < 4; ++mi) {
            int rowb = m0 + wr * 64 + mi * 16 + lq * 4;
            #pragma unroll
            for (int rr = 0; rr < 4; ++rr) {
                int row = rowb + rr;
                if (row >= N_TOT) continue;
                dst[(size_t)row * DIMM + cc] = __float2bfloat16(acc[mi][ni][rr] + bv);
            }
        }
    }
}

// ---------------------------------------------------------------------------
// Output projection (MFMA): O(16384x256 bf16) @ Wout + bout -> out fp32.
// 128x128 tile; A staged as direct short8 copy; B from Wt2.
// ---------------------------------------------------------------------------
__global__ __launch_bounds__(256) void out_mfma(
    const bf16* __restrict__ O, const bf16* __restrict__ Wt,
    const float* __restrict__ bias, float* __restrict__ out)
{
    __shared__ short As[128 * 64];
    __shared__ short Bs[128 * 64];
    const int t  = threadIdx.x;
    const int m0 = blockIdx.y * 128;
    const int n0 = blockIdx.x * 128;           // 0 or 128
    const int wid = t >> 6, lane = t & 63;
    const int wr = wid >> 1, wc = wid & 1;
    const int lm = lane & 15, lq = lane >> 4;

    f32x4 acc[4][4] = {};

    for (int k0 = 0; k0 < DIMM; k0 += 64) {
        if (k0) __syncthreads();
        #pragma unroll
        for (int i = 0; i < 4; ++i) {
            int c8 = t + 256 * i;
            int r  = c8 >> 3, kc = c8 & 7;
            short8 v = *(const short8*)((const short*)O + (size_t)(m0 + r) * DIMM + k0 + kc * 8);
            *(short8*)(As + r * 64 + swz(kc, r) * 8) = v;
        }
        #pragma unroll
        for (int i = 0; i < 4; ++i) {
            int c8 = t + 256 * i;
            int n  = c8 >> 3, kc = c8 & 7;
            short8 v = *(const short8*)((const short*)Wt + (size_t)(n0 + n) * 256 + k0 + kc * 8);
            *(short8*)(Bs + n * 64 + swz(kc, n) * 8) = v;
        }
        __syncthreads();
        #pragma unroll
        for (int kk = 0; kk < 2; ++kk) {
            const int c = kk * 4 + lq;
            short8 af[4], bfq[4];
            #pragma unroll
            for (int mi = 0; mi < 4; ++mi) {
                int r = wr * 64 + mi * 16 + lm;
                af[mi] = *(const short8*)(As + r * 64 + swz(c, r) * 8);
            }
            #pragma unroll
            for (int ni = 0; ni < 4; ++ni) {
                int n = wc * 64 + ni * 16 + lm;
                bfq[ni] = *(const short8*)(Bs + n * 64 + swz(c, n) * 8);
            }
            #pragma unroll
            for (int mi = 0; mi < 4; ++mi)
                #pragma unroll
                for (int ni = 0; ni < 4; ++ni)
                    acc[mi][ni] = __builtin_amdgcn_mfma_f32_16x16x32_bf16(
                        af[mi], bfq[ni], acc[mi][ni], 0, 0, 0);
        }
    }

    #pragma unroll
    for (int ni = 0; ni < 4; ++ni) {
        int col = n0 + wc * 64 + ni * 16 + lm;
        float bv = bias[col];
        #pragma unroll
        for (int mi = 0; mi < 4; ++mi) {
            int rowb = m0 + wr * 64 + mi * 16 + lq * 4;
            #pragma unroll
            for (int rr = 0; rr < 4; ++rr) {
                float val = acc[mi][ni][rr] + bv;
                val = fminf(fmaxf(val, -1e4f), 1e4f);  // tripwire (no-op valid)
                out[(size_t)(rowb + rr) * DIMM + col] = val;
            }
        }
    }
}

// ---------------------------------------------------------------------------
// CSR scan + fill (count lives in prep_kernel).
// ---------------------------------------------------------------------------
__global__ void scan_kernel(int* __restrict__ cnt_cursor, int* __restrict__ rowstart)
{
    __shared__ int part[256];
    const int t = threadIdx.x;
    const int base = t * 64;
    int s = 0;
    for (int i = 0; i < 64; ++i) s += cnt_cursor[base + i];
    part[t] = s;
    __syncthreads();
    for (int off = 1; off < 256; off <<= 1) {
        int v = (t >= off) ? part[t - off] : 0;
        __syncthreads();
        part[t] += v;
        __syncthreads();
    }
    int excl = part[t] - s;
    for (int i = 0; i < 64; ++i) {
        int v = cnt_cursor[base + i];
        rowstart[base + i]   = excl;
        cnt_cursor[base + i] = excl;
        excl += v;
    }
    if (t == 255) rowstart[N_NODES] = excl;
}

__global__ void fill_edges(const int* __restrict__ ei, const int* __restrict__ xei,
                           int* __restrict__ cursor, int* __restrict__ adj)
{
    int e = blockIdx.x * blockDim.x + threadIdx.x;
    int s, d;
    if (e < E_LOCAL)      { s = ei[e];            d = ei[E_LOCAL + e]; }
    else if (e < E_CSR)   { int ee = e - E_LOCAL; s = xei[ee]; d = xei[E_EXP + ee]; }
    else return;
    int pos = atomicAdd(&cursor[d], 1);
    adj[pos] = s;
}

// ---------------------------------------------------------------------------
// Gather attention: one wave per dst node; bf16 Q/K/V; 4-edge unroll (8
// gather loads in flight). Virtual edge index domain [rs-5, re): -5=self,
// -4..-1=globals, >=0 = adj[i]. Tripwires are no-ops on valid data.
// ---------------------------------------------------------------------------
__global__ __launch_bounds__(256) void attn_kernel(
    const bf16* __restrict__ Qb, const bf16* __restrict__ Kb,
    const bf16* __restrict__ Vb, const int* __restrict__ rowstart,
    const int* __restrict__ adj, bf16* __restrict__ Ob)
{
    const int wave = (blockIdx.x * blockDim.x + threadIdx.x) >> 6;
    const int lane = threadIdx.x & 63;
    if (wave >= N_NODES) return;
    const int n = wave;
    const float scale = 0.1767766952966369f;  // 32^-0.5

    const ushort4* K4 = (const ushort4*)Kb;
    const ushort4* V4 = (const ushort4*)Vb;

    ushort4 qu = ((const ushort4*)Qb)[(size_t)n * 64 + lane];
    float4 q;
    q.x = bu2f(qu.x) * scale; q.y = bu2f(qu.y) * scale;
    q.z = bu2f(qu.z) * scale; q.w = bu2f(qu.w) * scale;

    float4 acc = make_float4(0.f, 0.f, 0.f, 0.f);
    float dsum = 0.f;

    const int rs = rowstart[n];
    const int re = rowstart[n + 1];

    for (int i = rs - 5; i < re; i += 4) {
        int   sv[4];
        float ok[4];
        #pragma unroll
        for (int u = 0; u < 4; ++u) {
            int ii = i + u;
            bool v = (ii < re);
            int d = ii - rs;
            int s = v ? ((d < 0) ? ((d == -5) ? n : (N_NODES + d + 4)) : adj[ii]) : 0;
            sv[u] = min(max(s, 0), N_TOT - 1);
            ok[u] = v ? 1.f : 0.f;
        }
        ushort4 kv[4], vv[4];
        #pragma unroll
        for (int u = 0; u < 4; ++u) kv[u] = K4[(size_t)sv[u] * 64 + lane];
        #pragma unroll
        for (int u = 0; u < 4; ++u) vv[u] = V4[(size_t)sv[u] * 64 + lane];

        float p[4];
        #pragma unroll
        for (int u = 0; u < 4; ++u)
            p[u] = q.x * bu2f(kv[u].x) + q.y * bu2f(kv[u].y)
                 + q.z * bu2f(kv[u].z) + q.w * bu2f(kv[u].w);
        #pragma unroll
        for (int u = 0; u < 4; ++u) {
            p[u] += __shfl_xor(p[u], 1);
            p[u] += __shfl_xor(p[u], 2);
            p[u] += __shfl_xor(p[u], 4);
        }
        #pragma unroll
        for (int u = 0; u < 4; ++u) {
            float wgt = ok[u] * __expf(fminf(p[u], 80.f));
            dsum += wgt;
            acc.x += wgt * bu2f(vv[u].x);
            acc.y += wgt * bu2f(vv[u].y);
            acc.z += wgt * bu2f(vv[u].z);
            acc.w += wgt * bu2f(vv[u].w);
        }
    }

    float r = 1.0f / fmaxf(dsum, 1e-30f);    // tripwire
    ushort4 o;
    o.x = (unsigned short)__builtin_bit_cast(short, __float2bfloat16(fminf(fmaxf(acc.x * r, -500.f), 500.f)));
    o.y = (unsigned short)__builtin_bit_cast(short, __float2bfloat16(fminf(fmaxf(acc.y * r, -500.f), 500.f)));
    o.z = (unsigned short)__builtin_bit_cast(short, __float2bfloat16(fminf(fmaxf(acc.z * r, -500.f), 500.f)));
    o.w = (unsigned short)__builtin_bit_cast(short, __float2bfloat16(fminf(fmaxf(acc.w * r, -500.f), 500.f)));
    ((ushort4*)Ob)[(size_t)n * 64 + lane] = o;
}

// ---------------------------------------------------------------------------
extern "C" void kernel_launch(void* const* d_in, const int* in_sizes, int n_in,
                              void* d_out, int out_size, void* d_ws, size_t ws_size,
                              hipStream_t stream)
{
    const float* x    = (const float*)d_in[0];
    const int*   ei   = (const int*)d_in[1];
    const int*   xei  = (const int*)d_in[2];
    const float* Wqkv = (const float*)d_in[3];
    const float* bqkv = (const float*)d_in[4];
    const float* Wout = (const float*)d_in[5];
    const float* bout = (const float*)d_in[6];
    const float* gtok = (const float*)d_in[7];

    // workspace layout (~35 MB):
    int* rowstart = (int*)d_ws;               // N_NODES+1
    int* cursor   = rowstart + (N_NODES + 1); // N_NODES
    int* adj      = cursor + N_NODES;         // E_CSR
    const size_t int_bytes = (size_t)(N_NODES + 1 + N_NODES + E_CSR) * sizeof(int);
    uintptr_t fb = ((uintptr_t)(adj + E_CSR) + 15) & ~(uintptr_t)15;
    bf16*  Qb  = (bf16*)fb;                         // bf16, N_TOT*256
    bf16*  Kb  = Qb + (size_t)N_TOT * DIMM;         // bf16, N_TOT*256
    bf16*  Vb  = Kb + (size_t)N_TOT * DIMM;         // bf16, N_TOT*256
    bf16*  Ob  = Vb + (size_t)N_TOT * DIMM;         // bf16, N_NODES*256
    bf16*  Wt1 = Ob + (size_t)N_NODES * DIMM;       // bf16, 768*256
    bf16*  Wt2 = Wt1 + 768 * 256;                   // bf16, 256*256

    hipMemsetAsync(d_ws, 0, int_bytes, stream);

    prep_kernel<<<832, 256, 0, stream>>>(Wqkv, Wout, ei, xei, Wt1, Wt2, cursor);
    scan_kernel<<<1, 256, 0, stream>>>(cursor, rowstart);
    fill_edges<<<(E_CSR + 255) / 256, 256, 0, stream>>>(ei, xei, cursor, adj);
    qkv_mfma<<<dim3(6, 129), 256, 0, stream>>>(x, gtok, Wt1, bqkv, Qb, Kb, Vb);
    attn_kernel<<<N_NODES / 4, 256, 0, stream>>>(Qb, Kb, Vb, rowstart, adj, Ob);
    out_mfma<<<dim3(2, 128), 256, 0, stream>>>(Ob, Wt2, bout, (float*)d_out);
}

// Round 13
// 183.711 us; speedup vs baseline: 1.2751x; 1.0685x over previous
//
#include <hip/hip_runtime.h>
#include <hip/hip_bf16.h>
#include <stdint.h>

#define N_NODES   16384
#define DIMM      256
#define HEADS     8
#define HDIM      32
#define NUM_GLOBAL 4
#define N_TOT     (N_NODES + NUM_GLOBAL)   // 16388
#define E_LOCAL   131072
#define E_EXP     65536
#define E_CSR     (E_LOCAL + E_EXP)        // 196608

typedef __hip_bfloat16 bf16;
typedef __attribute__((ext_vector_type(8))) short short8;
typedef __attribute__((ext_vector_type(4))) short sh4;
typedef __attribute__((ext_vector_type(4))) float f32x4;

__device__ __forceinline__ short f2s(float f) {
    bf16 h = __float2bfloat16(f);
    return __builtin_bit_cast(short, h);
}
__device__ __forceinline__ float bu2f(unsigned short u) {
    return __bfloat162float(__builtin_bit_cast(bf16, u));
}

// XOR swizzle: 16B chunk c of row r stored at chunk (c ^ (r&7) ^ ((r>>3)&7)).
__device__ __forceinline__ int swz(int c, int r) {
    return c ^ (r & 7) ^ ((r >> 3) & 7);
}

// ---------------------------------------------------------------------------
// prep: (a) transpose Wqkv (256x768 fp32) -> Wt1 bf16 [768][256]
//       (b) transpose Wout (256x256 fp32) -> Wt2 bf16 [256][256]
//       (c) count_edges into cnt (dst-keyed; n2g edges skipped)
// ---------------------------------------------------------------------------
__global__ __launch_bounds__(256) void prep_kernel(
    const float* __restrict__ Wqkv, const float* __restrict__ Wout,
    const int* __restrict__ ei, const int* __restrict__ xei,
    bf16* __restrict__ Wt1, bf16* __restrict__ Wt2, int* __restrict__ cnt)
{
    const int b = blockIdx.x;
    const int t = threadIdx.x;
    if (b < 64) {
        __shared__ float T[64][65];
        const float* src; bf16* dst; int n0, k0, ldn;
        if (b < 48) { src = Wqkv; dst = Wt1; n0 = (b % 12) * 64; k0 = (b / 12) * 64; ldn = 768; }
        else        { int bb = b - 48; src = Wout; dst = Wt2; n0 = (bb & 3) * 64; k0 = (bb >> 2) * 64; ldn = 256; }
        #pragma unroll
        for (int i = 0; i < 4; ++i) {
            int idx = t + 256 * i;
            int r = idx >> 4, c4 = (idx & 15) * 4;
            float4 v = *(const float4*)(src + (size_t)(k0 + r) * ldn + n0 + c4);
            T[r][c4] = v.x; T[r][c4 + 1] = v.y; T[r][c4 + 2] = v.z; T[r][c4 + 3] = v.w;
        }
        __syncthreads();
        #pragma unroll
        for (int i = 0; i < 4; ++i) {
            int idx = t + 256 * i;
            int nr = idx >> 4, kk = (idx & 15) * 4;
            sh4 o;
            o[0] = f2s(T[kk][nr]);     o[1] = f2s(T[kk + 1][nr]);
            o[2] = f2s(T[kk + 2][nr]); o[3] = f2s(T[kk + 3][nr]);
            *(sh4*)(dst + (size_t)(n0 + nr) * 256 + k0 + kk) = o;
        }
    } else {
        int e = (b - 64) * 256 + t;
        if (e < E_LOCAL)      atomicAdd(&cnt[ei[E_LOCAL + e]], 1);
        else if (e < E_CSR) { int ee = e - E_LOCAL; atomicAdd(&cnt[xei[E_EXP + ee]], 1); }
    }
}

// ---------------------------------------------------------------------------
// QKV projection (MFMA): X_full(16388x256 fp32) @ Wqkv + b -> Q,K,V bf16.
// 128x128 tile / BK=64 / 4 waves (2x2) / 4x4 frags. Epilogue round-trips C
// through LDS (row stride 136 shorts: 16B-aligned rows, 4-bank skew) so
// global writes are full 16B chunks, row-contiguous -- kills the 3x HBM
// write amplification R12 measured (74.7 MB vs 25.2 ideal).
// ---------------------------------------------------------------------------
__global__ __launch_bounds__(256) void qkv_mfma(
    const float* __restrict__ x, const float* __restrict__ gtok,
    const bf16* __restrict__ Wt, const float* __restrict__ bias,
    bf16* __restrict__ Qb, bf16* __restrict__ Kb, bf16* __restrict__ Vb)
{
    __shared__ __align__(16) short SM[128 * 136];   // 34.8 KB union buffer
    short* As = SM;                  // [128][64] staging
    short* Bs = SM + 128 * 64;
    const int t  = threadIdx.x;
    const int m0 = blockIdx.y * 128;
    const int n0 = blockIdx.x * 128;           // 0..640
    const int wid = t >> 6, lane = t & 63;
    const int wr = wid >> 1, wc = wid & 1;
    const int lm = lane & 15, lq = lane >> 4;

    f32x4 acc[4][4] = {};

    for (int k0 = 0; k0 < DIMM; k0 += 64) {
        if (k0) __syncthreads();
        // --- stage A: 128 rows x 64 k; 4 short8 per thread (fp32->bf16) ---
        #pragma unroll
        for (int i = 0; i < 4; ++i) {
            int c8 = t + 256 * i;
            int r  = c8 >> 3, kc = c8 & 7;
            int row = m0 + r;
            float4 v0 = make_float4(0.f, 0.f, 0.f, 0.f), v1 = v0;
            if (row < N_NODES) {
                const float* p = x + (size_t)row * DIMM + k0 + kc * 8;
                v0 = *(const float4*)p; v1 = *(const float4*)(p + 4);
            } else if (row < N_TOT) {
                const float* p = gtok + (size_t)(row - N_NODES) * DIMM + k0 + kc * 8;
                v0 = *(const float4*)p; v1 = *(const float4*)(p + 4);
            }
            short8 o;
            o[0] = f2s(v0.x); o[1] = f2s(v0.y); o[2] = f2s(v0.z); o[3] = f2s(v0.w);
            o[4] = f2s(v1.x); o[5] = f2s(v1.y); o[6] = f2s(v1.z); o[7] = f2s(v1.w);
            *(short8*)(As + r * 64 + swz(kc, r) * 8) = o;
        }
        // --- stage B: direct short8 copy from Wt[n][k] ---
        #pragma unroll
        for (int i = 0; i < 4; ++i) {
            int c8 = t + 256 * i;
            int n  = c8 >> 3, kc = c8 & 7;
            short8 v = *(const short8*)((const short*)Wt + (size_t)(n0 + n) * 256 + k0 + kc * 8);
            *(short8*)(Bs + n * 64 + swz(kc, n) * 8) = v;
        }
        __syncthreads();
        #pragma unroll
        for (int kk = 0; kk < 2; ++kk) {
            const int c = kk * 4 + lq;
            short8 af[4], bfq[4];
            #pragma unroll
            for (int mi = 0; mi < 4; ++mi) {
                int r = wr * 64 + mi * 16 + lm;
                af[mi] = *(const short8*)(As + r * 64 + swz(c, r) * 8);
            }
            #pragma unroll
            for (int ni = 0; ni < 4; ++ni) {
                int n = wc * 64 + ni * 16 + lm;
                bfq[ni] = *(const short8*)(Bs + n * 64 + swz(c, n) * 8);
            }
            #pragma unroll
            for (int mi = 0; mi < 4; ++mi)
                #pragma unroll
                for (int ni = 0; ni < 4; ++ni)
                    acc[mi][ni] = __builtin_amdgcn_mfma_f32_16x16x32_bf16(
                        af[mi], bfq[ni], acc[mi][ni], 0, 0, 0);
        }
    }

    // --- epilogue phase 1: C fragments -> LDS (bf16, [r][c] stride 136) ---
    __syncthreads();
    #pragma unroll
    for (int ni = 0; ni < 4; ++ni) {
        int col = wc * 64 + ni * 16 + lm;           // tile col 0..127
        float bv = bias[n0 + col];
        #pragma unroll
        for (int mi = 0; mi < 4; ++mi) {
            int rowb = wr * 64 + mi * 16 + lq * 4;
            #pragma unroll
            for (int rr = 0; rr < 4; ++rr)
                SM[(rowb + rr) * 136 + col] = f2s(acc[mi][ni][rr] + bv);
        }
    }
    __syncthreads();
    // --- epilogue phase 2: coalesced row-contiguous 16B stores ---
    #pragma unroll
    for (int it = 0; it < 8; ++it) {
        int idx = it * 256 + t;                     // 0..2047
        int r = idx >> 4, c8 = idx & 15;
        int row = m0 + r;
        if (row < N_TOT) {
            int colbase = n0 + (c8 >> 3) * 64;      // 64-aligned stripe
            int sel = colbase >> 8;                 // 0=Q 1=K 2=V
            bf16* __restrict__ dst = (sel == 0) ? Qb : (sel == 1) ? Kb : Vb;
            int cc = (colbase & 255) + (c8 & 7) * 8;
            short8 v = *(const short8*)(SM + r * 136 + c8 * 8);
            *(short8*)((short*)dst + (size_t)row * DIMM + cc) = v;
        }
    }
}

// ---------------------------------------------------------------------------
// Output projection (MFMA): O(16384x256 bf16) @ Wout + bout -> out fp32.
// 128x128 tile; epilogue via LDS in two 64-row fp32 passes for coalesced
// full-line stores.
// ---------------------------------------------------------------------------
__global__ __launch_bounds__(256) void out_mfma(
    const bf16* __restrict__ O, const bf16* __restrict__ Wt,
    const float* __restrict__ bias, float* __restrict__ out)
{
    __shared__ __align__(16) short SM[128 * 136];
    short* As = SM;
    short* Bs = SM + 128 * 64;
    float* CF = (float*)SM;          // 64 x 132 fp32 pass buffer (33.8 KB)
    const int t  = threadIdx.x;
    const int m0 = blockIdx.y * 128;
    const int n0 = blockIdx.x * 128;           // 0 or 128
    const int wid = t >> 6, lane = t & 63;
    const int wr = wid >> 1, wc = wid & 1;
    const int lm = lane & 15, lq = lane >> 4;

    f32x4 acc[4][4] = {};

    for (int k0 = 0; k0 < DIMM; k0 += 64) {
        if (k0) __syncthreads();
        #pragma unroll
        for (int i = 0; i < 4; ++i) {
            int c8 = t + 256 * i;
            int r  = c8 >> 3, kc = c8 & 7;
            short8 v = *(const short8*)((const short*)O + (size_t)(m0 + r) * DIMM + k0 + kc * 8);
            *(short8*)(As + r * 64 + swz(kc, r) * 8) = v;
        }
        #pragma unroll
        for (int i = 0; i < 4; ++i) {
            int c8 = t + 256 * i;
            int n  = c8 >> 3, kc = c8 & 7;
            short8 v = *(const short8*)((const short*)Wt + (size_t)(n0 + n) * 256 + k0 + kc * 8);
            *(short8*)(Bs + n * 64 + swz(kc, n) * 8) = v;
        }
        __syncthreads();
        #pragma unroll
        for (int kk = 0; kk < 2; ++kk) {
            const int c = kk * 4 + lq;
            short8 af[4], bfq[4];
            #pragma unroll
            for (int mi = 0; mi < 4; ++mi) {
                int r = wr * 64 + mi * 16 + lm;
                af[mi] = *(const short8*)(As + r * 64 + swz(c, r) * 8);
            }
            #pragma unroll
            for (int ni = 0; ni < 4; ++ni) {
                int n = wc * 64 + ni * 16 + lm;
                bfq[ni] = *(const short8*)(Bs + n * 64 + swz(c, n) * 8);
            }
            #pragma unroll
            for (int mi = 0; mi < 4; ++mi)
                #pragma unroll
                for (int ni = 0; ni < 4; ++ni)
                    acc[mi][ni] = __builtin_amdgcn_mfma_f32_16x16x32_bf16(
                        af[mi], bfq[ni], acc[mi][ni], 0, 0, 0);
        }
    }

    // --- epilogue: two 64-row fp32 passes through LDS ---
    #pragma unroll
    for (int p = 0; p < 2; ++p) {
        __syncthreads();
        if (wr == p) {
            #pragma unroll
            for (int ni = 0; ni < 4; ++ni) {
                int col = wc * 64 + ni * 16 + lm;
                float bv = bias[n0 + col];
                #pragma unroll
                for (int mi = 0; mi < 4; ++mi) {
                    int lr = mi * 16 + lq * 4;
                    #pragma unroll
                    for (int rr = 0; rr < 4; ++rr) {
                        float val = acc[mi][ni][rr] + bv;
                        val = fminf(fmaxf(val, -1e4f), 1e4f);  // tripwire
                        CF[(lr + rr) * 132 + col] = val;
                    }
                }
            }
        }
        __syncthreads();
        #pragma unroll
        for (int it = 0; it < 8; ++it) {
            int idx = it * 256 + t;                 // 0..2047
            int r = idx >> 5, c4 = idx & 31;
            float4 v = *(const float4*)(CF + r * 132 + c4 * 4);
            *(float4*)(out + (size_t)(m0 + p * 64 + r) * DIMM + n0 + c4 * 4) = v;
        }
    }
}

// ---------------------------------------------------------------------------
// CSR scan + fill (count lives in prep_kernel).
// ---------------------------------------------------------------------------
__global__ void scan_kernel(int* __restrict__ cnt_cursor, int* __restrict__ rowstart)
{
    __shared__ int part[256];
    const int t = threadIdx.x;
    const int base = t * 64;
    int s = 0;
    for (int i = 0; i < 64; ++i) s += cnt_cursor[base + i];
    part[t] = s;
    __syncthreads();
    for (int off = 1; off < 256; off <<= 1) {
        int v = (t >= off) ? part[t - off] : 0;
        __syncthreads();
        part[t] += v;
        __syncthreads();
    }
    int excl = part[t] - s;
    for (int i = 0; i < 64; ++i) {
        int v = cnt_cursor[base + i];
        rowstart[base + i]   = excl;
        cnt_cursor[base + i] = excl;
        excl += v;
    }
    if (t == 255) rowstart[N_NODES] = excl;
}

__global__ void fill_edges(const int* __restrict__ ei, const int* __restrict__ xei,
                           int* __restrict__ cursor, int* __restrict__ adj)
{
    int e = blockIdx.x * blockDim.x + threadIdx.x;
    int s, d;
    if (e < E_LOCAL)      { s = ei[e];            d = ei[E_LOCAL + e]; }
    else if (e < E_CSR)   { int ee = e - E_LOCAL; s = xei[ee]; d = xei[E_EXP + ee]; }
    else return;
    int pos = atomicAdd(&cursor[d], 1);
    adj[pos] = s;
}

// ---------------------------------------------------------------------------
// Gather attention: one wave per dst node; bf16 Q/K/V; 4-edge unroll (8
// gather loads in flight). Virtual edge index domain [rs-5, re): -5=self,
// -4..-1=globals, >=0 = adj[i]. Tripwires are no-ops on valid data.
// ---------------------------------------------------------------------------
__global__ __launch_bounds__(256) void attn_kernel(
    const bf16* __restrict__ Qb, const bf16* __restrict__ Kb,
    const bf16* __restrict__ Vb, const int* __restrict__ rowstart,
    const int* __restrict__ adj, bf16* __restrict__ Ob)
{
    const int wave = (blockIdx.x * blockDim.x + threadIdx.x) >> 6;
    const int lane = threadIdx.x & 63;
    if (wave >= N_NODES) return;
    const int n = wave;
    const float scale = 0.1767766952966369f;  // 32^-0.5

    const ushort4* K4 = (const ushort4*)Kb;
    const ushort4* V4 = (const ushort4*)Vb;

    ushort4 qu = ((const ushort4*)Qb)[(size_t)n * 64 + lane];
    float4 q;
    q.x = bu2f(qu.x) * scale; q.y = bu2f(qu.y) * scale;
    q.z = bu2f(qu.z) * scale; q.w = bu2f(qu.w) * scale;

    float4 acc = make_float4(0.f, 0.f, 0.f, 0.f);
    float dsum = 0.f;

    const int rs = rowstart[n];
    const int re = rowstart[n + 1];

    for (int i = rs - 5; i < re; i += 4) {
        int   sv[4];
        float ok[4];
        #pragma unroll
        for (int u = 0; u < 4; ++u) {
            int ii = i + u;
            bool v = (ii < re);
            int d = ii - rs;
            int s = v ? ((d < 0) ? ((d == -5) ? n : (N_NODES + d + 4)) : adj[ii]) : 0;
            sv[u] = min(max(s, 0), N_TOT - 1);
            ok[u] = v ? 1.f : 0.f;
        }
        ushort4 kv[4], vv[4];
        #pragma unroll
        for (int u = 0; u < 4; ++u) kv[u] = K4[(size_t)sv[u] * 64 + lane];
        #pragma unroll
        for (int u = 0; u < 4; ++u) vv[u] = V4[(size_t)sv[u] * 64 + lane];

        float p[4];
        #pragma unroll
        for (int u = 0; u < 4; ++u)
            p[u] = q.x * bu2f(kv[u].x) + q.y * bu2f(kv[u].y)
                 + q.z * bu2f(kv[u].z) + q.w * bu2f(kv[u].w);
        #pragma unroll
        for (int u = 0; u < 4; ++u) {
            p[u] += __shfl_xor(p[u], 1);
            p[u] += __shfl_xor(p[u], 2);
            p[u] += __shfl_xor(p[u], 4);
        }
        #pragma unroll
        for (int u = 0; u < 4; ++u) {
            float wgt = ok[u] * __expf(fminf(p[u], 80.f));
            dsum += wgt;
            acc.x += wgt * bu2f(vv[u].x);
            acc.y += wgt * bu2f(vv[u].y);
            acc.z += wgt * bu2f(vv[u].z);
            acc.w += wgt * bu2f(vv[u].w);
        }
    }

    float r = 1.0f / fmaxf(dsum, 1e-30f);    // tripwire
    ushort4 o;
    o.x = (unsigned short)__builtin_bit_cast(short, __float2bfloat16(fminf(fmaxf(acc.x * r, -500.f), 500.f)));
    o.y = (unsigned short)__builtin_bit_cast(short, __float2bfloat16(fminf(fmaxf(acc.y * r, -500.f), 500.f)));
    o.z = (unsigned short)__builtin_bit_cast(short, __float2bfloat16(fminf(fmaxf(acc.z * r, -500.f), 500.f)));
    o.w = (unsigned short)__builtin_bit_cast(short, __float2bfloat16(fminf(fmaxf(acc.w * r, -500.f), 500.f)));
    ((ushort4*)Ob)[(size_t)n * 64 + lane] = o;
}

// ---------------------------------------------------------------------------
extern "C" void kernel_launch(void* const* d_in, const int* in_sizes, int n_in,
                              void* d_out, int out_size, void* d_ws, size_t ws_size,
                              hipStream_t stream)
{
    const float* x    = (const float*)d_in[0];
    const int*   ei   = (const int*)d_in[1];
    const int*   xei  = (const int*)d_in[2];
    const float* Wqkv = (const float*)d_in[3];
    const float* bqkv = (const float*)d_in[4];
    const float* Wout = (const float*)d_in[5];
    const float* bout = (const float*)d_in[6];
    const float* gtok = (const float*)d_in[7];

    // workspace layout (~35 MB):
    int* rowstart = (int*)d_ws;               // N_NODES+1
    int* cursor   = rowstart + (N_NODES + 1); // N_NODES
    int* adj      = cursor + N_NODES;         // E_CSR
    const size_t int_bytes = (size_t)(N_NODES + 1 + N_NODES + E_CSR) * sizeof(int);
    uintptr_t fb = ((uintptr_t)(adj + E_CSR) + 15) & ~(uintptr_t)15;
    bf16*  Qb  = (bf16*)fb;                         // bf16, N_TOT*256
    bf16*  Kb  = Qb + (size_t)N_TOT * DIMM;         // bf16, N_TOT*256
    bf16*  Vb  = Kb + (size_t)N_TOT * DIMM;         // bf16, N_TOT*256
    bf16*  Ob  = Vb + (size_t)N_TOT * DIMM;         // bf16, N_NODES*256
    bf16*  Wt1 = Ob + (size_t)N_NODES * DIMM;       // bf16, 768*256
    bf16*  Wt2 = Wt1 + 768 * 256;                   // bf16, 256*256

    hipMemsetAsync(d_ws, 0, int_bytes, stream);

    prep_kernel<<<832, 256, 0, stream>>>(Wqkv, Wout, ei, xei, Wt1, Wt2, cursor);
    scan_kernel<<<1, 256, 0, stream>>>(cursor, rowstart);
    fill_edges<<<(E_CSR + 255) / 256, 256, 0, stream>>>(ei, xei, cursor, adj);
    qkv_mfma<<<dim3(6, 129), 256, 0, stream>>>(x, gtok, Wt1, bqkv, Qb, Kb, Vb);
    attn_kernel<<<N_NODES / 4, 256, 0, stream>>>(Qb, Kb, Vb, rowstart, adj, Ob);
    out_mfma<<<dim3(2, 128), 256, 0, stream>>>(Ob, Wt2, bout, (float*)d_out);
}

// Round 14
// 179.558 us; speedup vs baseline: 1.3046x; 1.0231x over previous
//
#include <hip/hip_runtime.h>
#include <hip/hip_bf16.h>
#include <stdint.h>

#define N_NODES   16384
#define DIMM      256
#define HEADS     8
#define HDIM      32
#define NUM_GLOBAL 4
#define N_TOT     (N_NODES + NUM_GLOBAL)   // 16388
#define E_LOCAL   131072
#define E_EXP     65536
#define E_CSR     (E_LOCAL + E_EXP)        // 196608

typedef __hip_bfloat16 bf16;
typedef __attribute__((ext_vector_type(8))) short short8;
typedef __attribute__((ext_vector_type(4))) short sh4;
typedef __attribute__((ext_vector_type(4))) float f32x4;

__device__ __forceinline__ short f2s(float f) {
    bf16 h = __float2bfloat16(f);
    return __builtin_bit_cast(short, h);
}
__device__ __forceinline__ float bu2f(unsigned short u) {
    return __bfloat162float(__builtin_bit_cast(bf16, u));
}

// XOR swizzle: 16B chunk c of row r stored at chunk (c ^ (r&7) ^ ((r>>3)&7)).
__device__ __forceinline__ int swz(int c, int r) {
    return c ^ (r & 7) ^ ((r >> 3) & 7);
}

// ---------------------------------------------------------------------------
// prep: (a) transpose Wqkv (256x768 fp32) -> Wt1 bf16 [768][256]
//       (b) transpose Wout (256x256 fp32) -> Wt2 bf16 [256][256]
//       (c) count_edges into cnt (dst-keyed; n2g edges skipped)
// ---------------------------------------------------------------------------
__global__ __launch_bounds__(256) void prep_kernel(
    const float* __restrict__ Wqkv, const float* __restrict__ Wout,
    const int* __restrict__ ei, const int* __restrict__ xei,
    bf16* __restrict__ Wt1, bf16* __restrict__ Wt2, int* __restrict__ cnt)
{
    const int b = blockIdx.x;
    const int t = threadIdx.x;
    if (b < 64) {
        __shared__ float T[64][65];
        const float* src; bf16* dst; int n0, k0, ldn;
        if (b < 48) { src = Wqkv; dst = Wt1; n0 = (b % 12) * 64; k0 = (b / 12) * 64; ldn = 768; }
        else        { int bb = b - 48; src = Wout; dst = Wt2; n0 = (bb & 3) * 64; k0 = (bb >> 2) * 64; ldn = 256; }
        #pragma unroll
        for (int i = 0; i < 4; ++i) {
            int idx = t + 256 * i;
            int r = idx >> 4, c4 = (idx & 15) * 4;
            float4 v = *(const float4*)(src + (size_t)(k0 + r) * ldn + n0 + c4);
            T[r][c4] = v.x; T[r][c4 + 1] = v.y; T[r][c4 + 2] = v.z; T[r][c4 + 3] = v.w;
        }
        __syncthreads();
        #pragma unroll
        for (int i = 0; i < 4; ++i) {
            int idx = t + 256 * i;
            int nr = idx >> 4, kk = (idx & 15) * 4;
            sh4 o;
            o[0] = f2s(T[kk][nr]);     o[1] = f2s(T[kk + 1][nr]);
            o[2] = f2s(T[kk + 2][nr]); o[3] = f2s(T[kk + 3][nr]);
            *(sh4*)(dst + (size_t)(n0 + nr) * 256 + k0 + kk) = o;
        }
    } else {
        int e = (b - 64) * 256 + t;
        if (e < E_LOCAL)      atomicAdd(&cnt[ei[E_LOCAL + e]], 1);
        else if (e < E_CSR) { int ee = e - E_LOCAL; atomicAdd(&cnt[xei[E_EXP + ee]], 1); }
    }
}

// ---------------------------------------------------------------------------
// QKV projection (MFMA): X_full(16388x256 fp32) @ Wqkv + b -> Q,K,V bf16.
// 128x128 tile / BK=64 / 4 waves (2x2) / 4x4 frags. LDS epilogue for
// coalesced 16B stores (R13). NEW: 1-D grid with XCD swizzle -- all 6
// n-blocks of one m-slab share blockIdx%8, i.e. one XCD's L2, so the X slab
// is fetched from HBM once instead of 6x (R12: FETCH 50 MB vs 17 ideal).
// Grid: 8 xcd * 17 j * 6 n = 816 blocks; m = xcd + 8j, guarded m<129.
// ---------------------------------------------------------------------------
__global__ __launch_bounds__(256) void qkv_mfma(
    const float* __restrict__ x, const float* __restrict__ gtok,
    const bf16* __restrict__ Wt, const float* __restrict__ bias,
    bf16* __restrict__ Qb, bf16* __restrict__ Kb, bf16* __restrict__ Vb)
{
    const int b = blockIdx.x;
    const int xcd = b & 7;
    const int i = b >> 3;                      // 0..101
    const int mt = xcd + 8 * (i / 6);          // m-tile 0..135
    if (mt >= 129) return;
    const int m0 = mt * 128;
    const int n0 = (i % 6) * 128;              // 0..640

    __shared__ __align__(16) short SM[128 * 136];   // 34.8 KB union buffer
    short* As = SM;                  // [128][64] staging
    short* Bs = SM + 128 * 64;
    const int t  = threadIdx.x;
    const int wid = t >> 6, lane = t & 63;
    const int wr = wid >> 1, wc = wid & 1;
    const int lm = lane & 15, lq = lane >> 4;

    f32x4 acc[4][4] = {};

    for (int k0 = 0; k0 < DIMM; k0 += 64) {
        if (k0) __syncthreads();
        // --- stage A: 128 rows x 64 k; 4 short8 per thread (fp32->bf16) ---
        #pragma unroll
        for (int ii = 0; ii < 4; ++ii) {
            int c8 = t + 256 * ii;
            int r  = c8 >> 3, kc = c8 & 7;
            int row = m0 + r;
            float4 v0 = make_float4(0.f, 0.f, 0.f, 0.f), v1 = v0;
            if (row < N_NODES) {
                const float* p = x + (size_t)row * DIMM + k0 + kc * 8;
                v0 = *(const float4*)p; v1 = *(const float4*)(p + 4);
            } else if (row < N_TOT) {
                const float* p = gtok + (size_t)(row - N_NODES) * DIMM + k0 + kc * 8;
                v0 = *(const float4*)p; v1 = *(const float4*)(p + 4);
            }
            short8 o;
            o[0] = f2s(v0.x); o[1] = f2s(v0.y); o[2] = f2s(v0.z); o[3] = f2s(v0.w);
            o[4] = f2s(v1.x); o[5] = f2s(v1.y); o[6] = f2s(v1.z); o[7] = f2s(v1.w);
            *(short8*)(As + r * 64 + swz(kc, r) * 8) = o;
        }
        // --- stage B: direct short8 copy from Wt[n][k] ---
        #pragma unroll
        for (int ii = 0; ii < 4; ++ii) {
            int c8 = t + 256 * ii;
            int n  = c8 >> 3, kc = c8 & 7;
            short8 v = *(const short8*)((const short*)Wt + (size_t)(n0 + n) * 256 + k0 + kc * 8);
            *(short8*)(Bs + n * 64 + swz(kc, n) * 8) = v;
        }
        __syncthreads();
        #pragma unroll
        for (int kk = 0; kk < 2; ++kk) {
            const int c = kk * 4 + lq;
            short8 af[4], bfq[4];
            #pragma unroll
            for (int mi = 0; mi < 4; ++mi) {
                int r = wr * 64 + mi * 16 + lm;
                af[mi] = *(const short8*)(As + r * 64 + swz(c, r) * 8);
            }
            #pragma unroll
            for (int ni = 0; ni < 4; ++ni) {
                int n = wc * 64 + ni * 16 + lm;
                bfq[ni] = *(const short8*)(Bs + n * 64 + swz(c, n) * 8);
            }
            #pragma unroll
            for (int mi = 0; mi < 4; ++mi)
                #pragma unroll
                for (int ni = 0; ni < 4; ++ni)
                    acc[mi][ni] = __builtin_amdgcn_mfma_f32_16x16x32_bf16(
                        af[mi], bfq[ni], acc[mi][ni], 0, 0, 0);
        }
    }

    // --- epilogue phase 1: C fragments -> LDS (bf16, [r][c] stride 136) ---
    __syncthreads();
    #pragma unroll
    for (int ni = 0; ni < 4; ++ni) {
        int col = wc * 64 + ni * 16 + lm;
        float bv = bias[n0 + col];
        #pragma unroll
        for (int mi = 0; mi < 4; ++mi) {
            int rowb = wr * 64 + mi * 16 + lq * 4;
            #pragma unroll
            for (int rr = 0; rr < 4; ++rr)
                SM[(rowb + rr) * 136 + col] = f2s(acc[mi][ni][rr] + bv);
        }
    }
    __syncthreads();
    // --- epilogue phase 2: coalesced row-contiguous 16B stores ---
    #pragma unroll
    for (int it = 0; it < 8; ++it) {
        int idx = it * 256 + t;
        int r = idx >> 4, c8 = idx & 15;
        int row = m0 + r;
        if (row < N_TOT) {
            int colbase = n0 + (c8 >> 3) * 64;
            int sel = colbase >> 8;                 // 0=Q 1=K 2=V
            bf16* __restrict__ dst = (sel == 0) ? Qb : (sel == 1) ? Kb : Vb;
            int cc = (colbase & 255) + (c8 & 7) * 8;
            short8 v = *(const short8*)(SM + r * 136 + c8 * 8);
            *(short8*)((short*)dst + (size_t)row * DIMM + cc) = v;
        }
    }
}

// ---------------------------------------------------------------------------
// Output projection (MFMA): O(16384x256 bf16) @ Wout + bout -> out fp32.
// Same XCD swizzle (2 n-blocks per m-slab): 256 blocks, m = xcd + 8*(i/2).
// ---------------------------------------------------------------------------
__global__ __launch_bounds__(256) void out_mfma(
    const bf16* __restrict__ O, const bf16* __restrict__ Wt,
    const float* __restrict__ bias, float* __restrict__ out)
{
    const int b = blockIdx.x;
    const int xcd = b & 7;
    const int i = b >> 3;                      // 0..31
    const int m0 = (xcd + 8 * (i >> 1)) * 128; // exact cover 0..127
    const int n0 = (i & 1) * 128;

    __shared__ __align__(16) short SM[128 * 136];
    short* As = SM;
    short* Bs = SM + 128 * 64;
    float* CF = (float*)SM;
    const int t  = threadIdx.x;
    const int wid = t >> 6, lane = t & 63;
    const int wr = wid >> 1, wc = wid & 1;
    const int lm = lane & 15, lq = lane >> 4;

    f32x4 acc[4][4] = {};

    for (int k0 = 0; k0 < DIMM; k0 += 64) {
        if (k0) __syncthreads();
        #pragma unroll
        for (int ii = 0; ii < 4; ++ii) {
            int c8 = t + 256 * ii;
            int r  = c8 >> 3, kc = c8 & 7;
            short8 v = *(const short8*)((const short*)O + (size_t)(m0 + r) * DIMM + k0 + kc * 8);
            *(short8*)(As + r * 64 + swz(kc, r) * 8) = v;
        }
        #pragma unroll
        for (int ii = 0; ii < 4; ++ii) {
            int c8 = t + 256 * ii;
            int n  = c8 >> 3, kc = c8 & 7;
            short8 v = *(const short8*)((const short*)Wt + (size_t)(n0 + n) * 256 + k0 + kc * 8);
            *(short8*)(Bs + n * 64 + swz(kc, n) * 8) = v;
        }
        __syncthreads();
        #pragma unroll
        for (int kk = 0; kk < 2; ++kk) {
            const int c = kk * 4 + lq;
            short8 af[4], bfq[4];
            #pragma unroll
            for (int mi = 0; mi < 4; ++mi) {
                int r = wr * 64 + mi * 16 + lm;
                af[mi] = *(const short8*)(As + r * 64 + swz(c, r) * 8);
            }
            #pragma unroll
            for (int ni = 0; ni < 4; ++ni) {
                int n = wc * 64 + ni * 16 + lm;
                bfq[ni] = *(const short8*)(Bs + n * 64 + swz(c, n) * 8);
            }
            #pragma unroll
            for (int mi = 0; mi < 4; ++mi)
                #pragma unroll
                for (int ni = 0; ni < 4; ++ni)
                    acc[mi][ni] = __builtin_amdgcn_mfma_f32_16x16x32_bf16(
                        af[mi], bfq[ni], acc[mi][ni], 0, 0, 0);
        }
    }

    // --- epilogue: two 64-row fp32 passes through LDS ---
    #pragma unroll
    for (int p = 0; p < 2; ++p) {
        __syncthreads();
        if (wr == p) {
            #pragma unroll
            for (int ni = 0; ni < 4; ++ni) {
                int col = wc * 64 + ni * 16 + lm;
                float bv = bias[n0 + col];
                #pragma unroll
                for (int mi = 0; mi < 4; ++mi) {
                    int lr = mi * 16 + lq * 4;
                    #pragma unroll
                    for (int rr = 0; rr < 4; ++rr) {
                        float val = acc[mi][ni][rr] + bv;
                        val = fminf(fmaxf(val, -1e4f), 1e4f);  // tripwire
                        CF[(lr + rr) * 132 + col] = val;
                    }
                }
            }
        }
        __syncthreads();
        #pragma unroll
        for (int it = 0; it < 8; ++it) {
            int idx = it * 256 + t;
            int r = idx >> 5, c4 = idx & 31;
            float4 v = *(const float4*)(CF + r * 132 + c4 * 4);
            *(float4*)(out + (size_t)(m0 + p * 64 + r) * DIMM + n0 + c4 * 4) = v;
        }
    }
}

// ---------------------------------------------------------------------------
// CSR scan + fill (count lives in prep_kernel).
// ---------------------------------------------------------------------------
__global__ void scan_kernel(int* __restrict__ cnt_cursor, int* __restrict__ rowstart)
{
    __shared__ int part[256];
    const int t = threadIdx.x;
    const int base = t * 64;
    int s = 0;
    for (int i = 0; i < 64; ++i) s += cnt_cursor[base + i];
    part[t] = s;
    __syncthreads();
    for (int off = 1; off < 256; off <<= 1) {
        int v = (t >= off) ? part[t - off] : 0;
        __syncthreads();
        part[t] += v;
        __syncthreads();
    }
    int excl = part[t] - s;
    for (int i = 0; i < 64; ++i) {
        int v = cnt_cursor[base + i];
        rowstart[base + i]   = excl;
        cnt_cursor[base + i] = excl;
        excl += v;
    }
    if (t == 255) rowstart[N_NODES] = excl;
}

__global__ void fill_edges(const int* __restrict__ ei, const int* __restrict__ xei,
                           int* __restrict__ cursor, int* __restrict__ adj)
{
    int e = blockIdx.x * blockDim.x + threadIdx.x;
    int s, d;
    if (e < E_LOCAL)      { s = ei[e];            d = ei[E_LOCAL + e]; }
    else if (e < E_CSR)   { int ee = e - E_LOCAL; s = xei[ee]; d = xei[E_EXP + ee]; }
    else return;
    int pos = atomicAdd(&cursor[d], 1);
    adj[pos] = s;
}

// ---------------------------------------------------------------------------
// Gather attention: one wave per dst node; bf16 Q/K/V; 8-edge unroll (16
// gather loads in flight -- the loop is L2-latency-queue-bound, VALUBusy
// ~14%). Virtual edge index domain [rs-5, re): -5=self, -4..-1=globals,
// >=0 = adj[i]. Tripwires are no-ops on valid data.
// ---------------------------------------------------------------------------
__global__ __launch_bounds__(256) void attn_kernel(
    const bf16* __restrict__ Qb, const bf16* __restrict__ Kb,
    const bf16* __restrict__ Vb, const int* __restrict__ rowstart,
    const int* __restrict__ adj, bf16* __restrict__ Ob)
{
    const int wave = (blockIdx.x * blockDim.x + threadIdx.x) >> 6;
    const int lane = threadIdx.x & 63;
    if (wave >= N_NODES) return;
    const int n = wave;
    const float scale = 0.1767766952966369f;  // 32^-0.5

    const ushort4* K4 = (const ushort4*)Kb;
    const ushort4* V4 = (const ushort4*)Vb;

    ushort4 qu = ((const ushort4*)Qb)[(size_t)n * 64 + lane];
    float4 q;
    q.x = bu2f(qu.x) * scale; q.y = bu2f(qu.y) * scale;
    q.z = bu2f(qu.z) * scale; q.w = bu2f(qu.w) * scale;

    float4 acc = make_float4(0.f, 0.f, 0.f, 0.f);
    float dsum = 0.f;

    const int rs = rowstart[n];
    const int re = rowstart[n + 1];

    for (int i = rs - 5; i < re; i += 8) {
        int   sv[8];
        float ok[8];
        #pragma unroll
        for (int u = 0; u < 8; ++u) {
            int ii = i + u;
            bool v = (ii < re);
            int d = ii - rs;
            int s = v ? ((d < 0) ? ((d == -5) ? n : (N_NODES + d + 4)) : adj[ii]) : 0;
            sv[u] = min(max(s, 0), N_TOT - 1);
            ok[u] = v ? 1.f : 0.f;
        }
        ushort4 kv[8], vv[8];
        #pragma unroll
        for (int u = 0; u < 8; ++u) kv[u] = K4[(size_t)sv[u] * 64 + lane];
        #pragma unroll
        for (int u = 0; u < 8; ++u) vv[u] = V4[(size_t)sv[u] * 64 + lane];

        float p[8];
        #pragma unroll
        for (int u = 0; u < 8; ++u)
            p[u] = q.x * bu2f(kv[u].x) + q.y * bu2f(kv[u].y)
                 + q.z * bu2f(kv[u].z) + q.w * bu2f(kv[u].w);
        #pragma unroll
        for (int u = 0; u < 8; ++u) {
            p[u] += __shfl_xor(p[u], 1);
            p[u] += __shfl_xor(p[u], 2);
            p[u] += __shfl_xor(p[u], 4);
        }
        #pragma unroll
        for (int u = 0; u < 8; ++u) {
            float wgt = ok[u] * __expf(fminf(p[u], 80.f));
            dsum += wgt;
            acc.x += wgt * bu2f(vv[u].x);
            acc.y += wgt * bu2f(vv[u].y);
            acc.z += wgt * bu2f(vv[u].z);
            acc.w += wgt * bu2f(vv[u].w);
        }
    }

    float r = 1.0f / fmaxf(dsum, 1e-30f);    // tripwire
    ushort4 o;
    o.x = (unsigned short)__builtin_bit_cast(short, __float2bfloat16(fminf(fmaxf(acc.x * r, -500.f), 500.f)));
    o.y = (unsigned short)__builtin_bit_cast(short, __float2bfloat16(fminf(fmaxf(acc.y * r, -500.f), 500.f)));
    o.z = (unsigned short)__builtin_bit_cast(short, __float2bfloat16(fminf(fmaxf(acc.z * r, -500.f), 500.f)));
    o.w = (unsigned short)__builtin_bit_cast(short, __float2bfloat16(fminf(fmaxf(acc.w * r, -500.f), 500.f)));
    ((ushort4*)Ob)[(size_t)n * 64 + lane] = o;
}

// ---------------------------------------------------------------------------
extern "C" void kernel_launch(void* const* d_in, const int* in_sizes, int n_in,
                              void* d_out, int out_size, void* d_ws, size_t ws_size,
                              hipStream_t stream)
{
    const float* x    = (const float*)d_in[0];
    const int*   ei   = (const int*)d_in[1];
    const int*   xei  = (const int*)d_in[2];
    const float* Wqkv = (const float*)d_in[3];
    const float* bqkv = (const float*)d_in[4];
    const float* Wout = (const float*)d_in[5];
    const float* bout = (const float*)d_in[6];
    const float* gtok = (const float*)d_in[7];

    // workspace layout (~35 MB):
    int* rowstart = (int*)d_ws;               // N_NODES+1
    int* cursor   = rowstart + (N_NODES + 1); // N_NODES
    int* adj      = cursor + N_NODES;         // E_CSR (fully written by fill_edges)
    uintptr_t fb = ((uintptr_t)(adj + E_CSR) + 15) & ~(uintptr_t)15;
    bf16*  Qb  = (bf16*)fb;                         // bf16, N_TOT*256
    bf16*  Kb  = Qb + (size_t)N_TOT * DIMM;         // bf16, N_TOT*256
    bf16*  Vb  = Kb + (size_t)N_TOT * DIMM;         // bf16, N_TOT*256
    bf16*  Ob  = Vb + (size_t)N_TOT * DIMM;         // bf16, N_NODES*256
    bf16*  Wt1 = Ob + (size_t)N_NODES * DIMM;       // bf16, 768*256
    bf16*  Wt2 = Wt1 + 768 * 256;                   // bf16, 256*256

    // only cursor needs zeroing (adj is bijectively written by fill_edges)
    hipMemsetAsync(cursor, 0, N_NODES * sizeof(int), stream);

    prep_kernel<<<832, 256, 0, stream>>>(Wqkv, Wout, ei, xei, Wt1, Wt2, cursor);
    scan_kernel<<<1, 256, 0, stream>>>(cursor, rowstart);
    fill_edges<<<(E_CSR + 255) / 256, 256, 0, stream>>>(ei, xei, cursor, adj);
    qkv_mfma<<<816, 256, 0, stream>>>(x, gtok, Wt1, bqkv, Qb, Kb, Vb);
    attn_kernel<<<N_NODES / 4, 256, 0, stream>>>(Qb, Kb, Vb, rowstart, adj, Ob);
    out_mfma<<<256, 256, 0, stream>>>(Ob, Wt2, bout, (float*)d_out);
}